// Round 16
// baseline (116.244 us; speedup 1.0000x reference)
//
#include <hip/hip_runtime.h>
#include <hip/hip_bf16.h>
#include <math.h>

// PNA layer, R16: persistent blocks + cross-group software pipeline.
// While computing group g's tiles, ALL of group g+1's operand loads are in
// flight (u8 gathers, v, edges, h, nbr) -> memory pipe never idles (the
// R8-R15 invariant wall was ~25% memory duty cycle from load/compute convoys).
//   u = h@W1 + b_pre -> offset-int8 (scale 16); v = h@W2 (bf16)
//   per group (16 nodes): acc = mfma32x32x16(ea,W3,0); e = relu(acc+u/16-8+v)
//   agg=[mean,max,min,std]; y1 = relu([h,agg]@Wfull + b1); out = y1@Wp2 + b2 + h
// MFMA layouts: 16x16x32 (m89-verified), 32x32x16 C/D (m74/m101-verified).

#define N_NODES 65536
#define NBLK (N_NODES / 16)       // 4096 groups
#define NITER 4
#define GRID_MAIN (NBLK / NITER)  // 1024 persistent blocks
#define GRID_PREP (NBLK + 64)
#define ASTRIDE 348   // A_lds row stride (u16)
#define YSTRIDE 76    // y1_lds row stride (u16)

typedef float f32x4 __attribute__((ext_vector_type(4)));
typedef float f32x16 __attribute__((ext_vector_type(16)));
typedef short s16x8 __attribute__((ext_vector_type(8)));
typedef unsigned short us4 __attribute__((ext_vector_type(4)));
typedef int i32x4 __attribute__((ext_vector_type(4)));

__device__ __forceinline__ unsigned short f2bf(float f) {     // manual RNE
    union { float f; unsigned int u; } v; v.f = f;
    unsigned int r = v.u + 0x7fffu + ((v.u >> 16) & 1u);
    return (unsigned short)(r >> 16);
}
__device__ __forceinline__ unsigned short f2bfh(float f) {    // compiler cvt
    __hip_bfloat16 b = __float2bfloat16(f);
    union { __hip_bfloat16 b; unsigned short u; } v; v.b = b; return v.u;
}
__device__ __forceinline__ float bf2f(unsigned short u) {
    union { unsigned int u; float f; } v; v.u = ((unsigned int)u) << 16; return v.f;
}
__device__ __forceinline__ unsigned char enc_u8(float x) {    // offset-int8, scale 16
    int q = __float2int_rn(x * 16.f) + 128;
    q = q < 0 ? 0 : (q > 255 ? 255 : q);
    return (unsigned char)q;
}

// ---------------- prep: u/v via MFMA (blocks < NBLK) + weight transpose ----------------
__global__ __launch_bounds__(256) void k_prep(const float* __restrict__ h,
                                              const float* __restrict__ Wpre,
                                              const float* __restrict__ b_pre,
                                              const float* __restrict__ Wp1,
                                              const float* __restrict__ Wp2,
                                              unsigned char* __restrict__ u8,
                                              unsigned short* __restrict__ vbf,
                                              unsigned short* __restrict__ wfullT,
                                              unsigned short* __restrict__ w3T,
                                              unsigned short* __restrict__ wp2T,
                                              float c1, float c2) {
    int t = threadIdx.x;
    if (blockIdx.x >= NBLK) {
        int c = blockIdx.x - NBLK;     // output col 0..63
        for (int k = t; k < 320; k += 256) {
            float v;
            if (k < 64) v = Wp1[k * 64 + c];
            else {
                int kk = k - 64;
                v = Wp1[(64 + kk) * 64 + c] + c1 * Wp1[(320 + kk) * 64 + c]
                                            + c2 * Wp1[(576 + kk) * 64 + c];
            }
            wfullT[c * 320 + k] = f2bf(v);
        }
        if (t < 16)              w3T[c * 16 + t]         = f2bf(Wpre[(128 + t) * 64 + c]);
        if (t >= 64 && t < 128)  wp2T[c * 64 + (t - 64)] = f2bf(Wp2[(t - 64) * 64 + c]);
        return;
    }

    // ---- uv blocks: [u|v] = h @ [W1|W2], 16 nodes, 4 waves x 32 cols ----
    __shared__ unsigned short hl[16 * 68];
    int lane = t & 63;
    int wv = __builtin_amdgcn_readfirstlane(t) >> 6;   // wave id (uniform)
    int c = lane & 15, g = lane >> 4;
    int node0 = blockIdx.x * 16;
    {
        int r = t >> 4, q = t & 15;
        float4 hv = *((const float4*)(h + (size_t)node0 * 64) + t);
        us4 o;
        o.x = f2bfh(hv.x); o.y = f2bfh(hv.y); o.z = f2bfh(hv.z); o.w = f2bfh(hv.w);
        *(us4*)&hl[r * 68 + q * 4] = o;
    }
    s16x8 bf[2][2];
    int woff = (wv < 2) ? 0 : 64;
    #pragma unroll
    for (int i2 = 0; i2 < 2; ++i2) {
        int wcol = ((wv & 1) * 32) + i2 * 16 + c;
        #pragma unroll
        for (int ks = 0; ks < 2; ++ks) {
            #pragma unroll
            for (int j = 0; j < 8; ++j)
                bf[i2][ks][j] = (short)f2bfh(Wpre[(woff + ks * 32 + g * 8 + j) * 64 + wcol]);
        }
    }
    __syncthreads();
    f32x4 acc0 = {0.f, 0.f, 0.f, 0.f}, acc1 = {0.f, 0.f, 0.f, 0.f};
    #pragma unroll
    for (int ks = 0; ks < 2; ++ks) {
        s16x8 a = *(const s16x8*)&hl[c * 68 + ks * 32 + g * 8];
        acc0 = __builtin_amdgcn_mfma_f32_16x16x32_bf16(a, bf[0][ks], acc0, 0, 0, 0);
        acc1 = __builtin_amdgcn_mfma_f32_16x16x32_bf16(a, bf[1][ks], acc1, 0, 0, 0);
    }
    #pragma unroll
    for (int i2 = 0; i2 < 2; ++i2) {
        int dcol = ((wv & 1) * 32) + i2 * 16 + c;
        const f32x4& av = i2 ? acc1 : acc0;
        if (wv < 2) {
            float bp = b_pre[dcol];
            #pragma unroll
            for (int i = 0; i < 4; ++i) {
                int row = g * 4 + i;
                u8[(size_t)(node0 + row) * 64 + dcol] = enc_u8(av[i] + bp);
            }
        } else {
            #pragma unroll
            for (int i = 0; i < 4; ++i) {
                int row = g * 4 + i;
                vbf[(size_t)(node0 + row) * 64 + dcol] = f2bfh(av[i]);
            }
        }
    }
}

// ---------------- fused main: persistent, 4 pipelined groups per block ----------------
__global__ __launch_bounds__(256, 3) void k_main(
    const float* __restrict__ h,
    const float* __restrict__ edge_attr,
    const int* __restrict__ nbr_idx,
    const float* __restrict__ b_post1,
    const float* __restrict__ b_post2,
    const unsigned char* __restrict__ u8,       // [N][64] offset-int8 (4 MB, L2-fit)
    const unsigned short* __restrict__ vbf,     // [N][64] bf16
    const unsigned short* __restrict__ wfullT,  // [64][320] bf16 (L2-resident)
    const unsigned short* __restrict__ w3T,     // [64][16]
    const unsigned short* __restrict__ wp2T,    // [64][64]
    float* __restrict__ out) {
    __shared__ unsigned char  u_lds[2][16384];   // 32768 B gathered u8 rows [256][64]
    __shared__ unsigned short v_lds[2][1024];    // 4096 B  v bf16 [16][64]
    __shared__ unsigned short A_lds[16 * ASTRIDE];   // 11136 B
    __shared__ unsigned short y1_lds[16 * YSTRIDE];  // 2432 B  -> 50432 B total

    int t = threadIdx.x;
    int lane = t & 63;
    int wu2 = __builtin_amdgcn_readfirstlane(t) >> 6;   // wave id (uniform)
    int c = lane & 15;          // 16x16 frag col / A-row
    int g = lane >> 4;          // 16x16 k-group
    int l32 = lane & 31;        // 32x32 frag row/col
    int h2 = lane >> 5;         // 32x32 k-half
    int ct = wu2 & 1;           // 32-col tile (uniform)
    int wr = wu2 >> 1;          // row-tile base (uniform)
    int colb = ct * 32 + l32;   // pretrans output col
    int col16 = wu2 * 16 + c;   // post1/post2 output col
    int ch = t & 3;             // staging 16B chunk
    int srow = t >> 2;          // staging row base (+64*i)

    s16x8 w3b = *(const s16x8*)&w3T[colb * 16 + h2 * 8];
    float b1c = b_post1[col16];
    float b2c = b_post2[col16];

    int grp0 = blockIdx.x * NITER;
    float4 xaC[4], xbC[4], xaN[4], xbN[4];
    int jc[4], jn[4];

    // ---------- prologue: stage group grp0; preload nbr for grp0+1 ----------
    {
        const int* nb = nbr_idx + (size_t)grp0 * 256;
        i32x4 s[4];
        #pragma unroll
        for (int i = 0; i < 4; ++i) {
            int j = nb[srow + 64 * i];
            s[i] = *(const i32x4*)(u8 + ((size_t)j << 6) + ch * 16);
        }
        i32x4 sv = {};
        if (t < 128)
            sv = *(const i32x4*)((const char*)vbf + (size_t)grp0 * 2048 + t * 16);
        const char* eb = (const char*)edge_attr
                       + ((size_t)grp0 * 256 + wr * 32 + l32) * 64 + h2 * 32;
        #pragma unroll
        for (int k = 0; k < 4; ++k) {
            xaC[k] = *(const float4*)(eb + k * 4096);
            xbC[k] = *(const float4*)(eb + k * 4096 + 16);
        }
        float4 hv = *((const float4*)(h + (size_t)grp0 * 1024) + t);
        #pragma unroll
        for (int i = 0; i < 4; ++i)
            jc[i] = nbr_idx[(size_t)(grp0 + 1) * 256 + srow + 64 * i];
        #pragma unroll
        for (int i = 0; i < 4; ++i)
            *(i32x4*)&u_lds[0][i * 4096 + t * 16] = s[i];
        if (t < 128) *(i32x4*)&v_lds[0][t * 8] = sv;
        {
            int r = t >> 4, q = t & 15;
            us4 o;
            o.x = f2bfh(hv.x); o.y = f2bfh(hv.y); o.z = f2bfh(hv.z); o.w = f2bfh(hv.w);
            *(us4*)&A_lds[r * ASTRIDE + q * 4] = o;
        }
    }
    __syncthreads();

    int b = 0;
    for (int it = 0; it < NITER; ++it) {
        int grp = grp0 + it;
        size_t node0 = (size_t)grp * 16;
        bool pf = (it + 1 < NITER);
        int grpn = grp + 1;

        // ---- issue ALL prefetch loads for group it+1 (latency hides under tiles) ----
        i32x4 su[4]; i32x4 sv = {}; float4 hn = {0.f, 0.f, 0.f, 0.f};
        if (pf) {
            #pragma unroll
            for (int i = 0; i < 4; ++i)
                su[i] = *(const i32x4*)(u8 + ((size_t)jc[i] << 6) + ch * 16);
            if (t < 128)
                sv = *(const i32x4*)((const char*)vbf + (size_t)grpn * 2048 + t * 16);
            const char* ebn = (const char*)edge_attr
                            + ((size_t)grpn * 256 + wr * 32 + l32) * 64 + h2 * 32;
            #pragma unroll
            for (int k = 0; k < 4; ++k) {
                xaN[k] = *(const float4*)(ebn + k * 4096);
                xbN[k] = *(const float4*)(ebn + k * 4096 + 16);
            }
            hn = *((const float4*)(h + (size_t)grpn * 1024) + t);
            if (it + 2 < NITER) {
                #pragma unroll
                for (int i = 0; i < 4; ++i)
                    jn[i] = nbr_idx[(size_t)(grp + 2) * 256 + srow + 64 * i];
            }
        }

        // ---- tiles: 4x 32x32x16 MFMA + stats on buf b ----
#define TILEC(IT) {                                                            \
    int rt = wr + 2 * (IT);                                                    \
    s16x8 a;                                                                   \
    a[0] = (short)f2bfh(xaC[IT].x); a[1] = (short)f2bfh(xaC[IT].y);            \
    a[2] = (short)f2bfh(xaC[IT].z); a[3] = (short)f2bfh(xaC[IT].w);            \
    a[4] = (short)f2bfh(xbC[IT].x); a[5] = (short)f2bfh(xbC[IT].y);            \
    a[6] = (short)f2bfh(xbC[IT].z); a[7] = (short)f2bfh(xbC[IT].w);            \
    f32x16 acc = {};                                                           \
    acc = __builtin_amdgcn_mfma_f32_32x32x16_bf16(a, w3b, acc, 0, 0, 0);       \
    const unsigned char* ur = &u_lds[b][(rt * 32 + 4 * h2) * 64 + colb];       \
    float uf[16];                                                              \
    _Pragma("unroll")                                                          \
    for (int q = 0; q < 4; ++q) {                                              \
        uf[4 * q + 0] = (float)ur[(8 * q + 0) * 64];                           \
        uf[4 * q + 1] = (float)ur[(8 * q + 1) * 64];                           \
        uf[4 * q + 2] = (float)ur[(8 * q + 2) * 64];                           \
        uf[4 * q + 3] = (float)ur[(8 * q + 3) * 64];                           \
    }                                                                          \
    float vv0 = bf2f(v_lds[b][(2 * rt + 0) * 64 + colb]) - 8.f;                \
    float vv1 = bf2f(v_lds[b][(2 * rt + 1) * 64 + colb]) - 8.f;                \
    float e0  = fmaxf(fmaf(uf[0],  0.0625f, acc[0]  + vv0), 0.f);              \
    float e1  = fmaxf(fmaf(uf[1],  0.0625f, acc[1]  + vv0), 0.f);              \
    float e2  = fmaxf(fmaf(uf[2],  0.0625f, acc[2]  + vv0), 0.f);              \
    float e3  = fmaxf(fmaf(uf[3],  0.0625f, acc[3]  + vv0), 0.f);              \
    float e4  = fmaxf(fmaf(uf[4],  0.0625f, acc[4]  + vv0), 0.f);              \
    float e5  = fmaxf(fmaf(uf[5],  0.0625f, acc[5]  + vv0), 0.f);              \
    float e6  = fmaxf(fmaf(uf[6],  0.0625f, acc[6]  + vv0), 0.f);              \
    float e7  = fmaxf(fmaf(uf[7],  0.0625f, acc[7]  + vv0), 0.f);              \
    float e8  = fmaxf(fmaf(uf[8],  0.0625f, acc[8]  + vv1), 0.f);              \
    float e9  = fmaxf(fmaf(uf[9],  0.0625f, acc[9]  + vv1), 0.f);              \
    float e10 = fmaxf(fmaf(uf[10], 0.0625f, acc[10] + vv1), 0.f);              \
    float e11 = fmaxf(fmaf(uf[11], 0.0625f, acc[11] + vv1), 0.f);              \
    float e12 = fmaxf(fmaf(uf[12], 0.0625f, acc[12] + vv1), 0.f);              \
    float e13 = fmaxf(fmaf(uf[13], 0.0625f, acc[13] + vv1), 0.f);              \
    float e14 = fmaxf(fmaf(uf[14], 0.0625f, acc[14] + vv1), 0.f);              \
    float e15 = fmaxf(fmaf(uf[15], 0.0625f, acc[15] + vv1), 0.f);              \
    float s1a = ((e0 + e1) + (e2 + e3)) + ((e4 + e5) + (e6 + e7));             \
    float s2a = fmaf(e0, e0, fmaf(e1, e1, fmaf(e2, e2, e3 * e3)))              \
              + fmaf(e4, e4, fmaf(e5, e5, fmaf(e6, e6, e7 * e7)));             \
    float mxa = fmaxf(fmaxf(fmaxf(e0, e1), fmaxf(e2, e3)),                     \
                      fmaxf(fmaxf(e4, e5), fmaxf(e6, e7)));                    \
    float mna = fminf(fminf(fminf(e0, e1), fminf(e2, e3)),                     \
                      fminf(fminf(e4, e5), fminf(e6, e7)));                    \
    float s1b = ((e8 + e9) + (e10 + e11)) + ((e12 + e13) + (e14 + e15));       \
    float s2b = fmaf(e8, e8, fmaf(e9, e9, fmaf(e10, e10, e11 * e11)))          \
              + fmaf(e12, e12, fmaf(e13, e13, fmaf(e14, e14, e15 * e15)));     \
    float mxb = fmaxf(fmaxf(fmaxf(e8, e9), fmaxf(e10, e11)),                   \
                      fmaxf(fmaxf(e12, e13), fmaxf(e14, e15)));                \
    float mnb = fminf(fminf(fminf(e8, e9), fminf(e10, e11)),                   \
                      fminf(fminf(e12, e13), fminf(e14, e15)));                \
    s1a += __shfl_xor(s1a, 32); s2a += __shfl_xor(s2a, 32);                    \
    mxa = fmaxf(mxa, __shfl_xor(mxa, 32)); mna = fminf(mna, __shfl_xor(mna, 32)); \
    s1b += __shfl_xor(s1b, 32); s2b += __shfl_xor(s2b, 32);                    \
    mxb = fmaxf(mxb, __shfl_xor(mxb, 32)); mnb = fminf(mnb, __shfl_xor(mnb, 32)); \
    float S1 = h2 ? s1b : s1a;                                                 \
    float S2 = h2 ? s2b : s2a;                                                 \
    float MX = h2 ? mxb : mxa;                                                 \
    float MN = h2 ? mnb : mna;                                                 \
    float M  = S1 * 0.0625f;                                                   \
    float SD = sqrtf(fmaxf(fmaf(-M, M, S2 * 0.0625f), 0.f) + 1e-5f);           \
    unsigned short* pd = &A_lds[(2 * rt + h2) * ASTRIDE + 64 + colb];          \
    pd[0]   = f2bfh(M);                                                        \
    pd[64]  = f2bfh(MX);                                                       \
    pd[128] = f2bfh(MN);                                                       \
    pd[192] = f2bfh(SD);                                                       \
}
        TILEC(0)
        TILEC(1)
        TILEC(2)
        TILEC(3)
#undef TILEC

        // ---- write prefetched u/v into buf b^1 (vmcnt wait lands HERE, after tiles) ----
        if (pf) {
            #pragma unroll
            for (int i = 0; i < 4; ++i)
                *(i32x4*)&u_lds[b ^ 1][i * 4096 + t * 16] = su[i];
            if (t < 128) *(i32x4*)&v_lds[b ^ 1][t * 8] = sv;
        }

        // ---- hoist post1 weight loads ----
        s16x8 wf[10];
        #pragma unroll
        for (int ks = 0; ks < 10; ++ks)
            wf[ks] = *(const s16x8*)&wfullT[col16 * 320 + ks * 32 + g * 8];
        __syncthreads();   // barrier(1): agg + next-buf staging visible

        // ---- post1: y1 = relu([h,agg]@Wfull + b1), K=320 ----
        {
            f32x4 y1 = {0.f, 0.f, 0.f, 0.f};
            #pragma unroll
            for (int ks = 0; ks < 10; ++ks) {
                s16x8 a = *(const s16x8*)&A_lds[c * ASTRIDE + ks * 32 + g * 8];
                y1 = __builtin_amdgcn_mfma_f32_16x16x32_bf16(a, wf[ks], y1, 0, 0, 0);
            }
            #pragma unroll
            for (int i = 0; i < 4; ++i)
                y1_lds[(g * 4 + i) * YSTRIDE + col16] = f2bfh(fmaxf(y1[i] + b1c, 0.f));
        }
        s16x8 wp0 = *(const s16x8*)&wp2T[col16 * 64 + 0 * 32 + g * 8];
        s16x8 wp1 = *(const s16x8*)&wp2T[col16 * 64 + 1 * 32 + g * 8];
        __syncthreads();   // barrier(2): y1 visible, A_lds reads done

        // ---- write h(it+1) into A_lds h-region (A free until next post1) ----
        if (pf) {
            int r = t >> 4, q = t & 15;
            us4 o;
            o.x = f2bfh(hn.x); o.y = f2bfh(hn.y); o.z = f2bfh(hn.z); o.w = f2bfh(hn.w);
            *(us4*)&A_lds[r * ASTRIDE + q * 4] = o;
        }

        // ---- post2 + residual ----
        {
            f32x4 o = {0.f, 0.f, 0.f, 0.f};
            s16x8 a0 = *(const s16x8*)&y1_lds[c * YSTRIDE + 0 * 32 + g * 8];
            s16x8 a1 = *(const s16x8*)&y1_lds[c * YSTRIDE + 1 * 32 + g * 8];
            o = __builtin_amdgcn_mfma_f32_16x16x32_bf16(a0, wp0, o, 0, 0, 0);
            o = __builtin_amdgcn_mfma_f32_16x16x32_bf16(a1, wp1, o, 0, 0, 0);
            #pragma unroll
            for (int i = 0; i < 4; ++i) {
                int r = g * 4 + i;
                out[(node0 + r) * 64 + col16] =
                    o[i] + b2c + h[(node0 + r) * 64 + col16];
            }
        }

        // ---- rotate pipeline state ----
        if (pf) {
            #pragma unroll
            for (int k = 0; k < 4; ++k) { xaC[k] = xaN[k]; xbC[k] = xbN[k]; }
            #pragma unroll
            for (int i = 0; i < 4; ++i) jc[i] = jn[i];
            b ^= 1;
        }
    }
}

extern "C" void kernel_launch(void* const* d_in, const int* in_sizes, int n_in,
                              void* d_out, int out_size, void* d_ws, size_t ws_size,
                              hipStream_t stream) {
    const float* h         = (const float*)d_in[0];
    const float* edge_attr = (const float*)d_in[1];
    const int*   nbr_idx   = (const int*)d_in[2];
    const float* W_pre     = (const float*)d_in[3];
    const float* b_pre     = (const float*)d_in[4];
    const float* W_post1   = (const float*)d_in[5];
    const float* b_post1   = (const float*)d_in[6];
    const float* W_post2   = (const float*)d_in[7];
    const float* b_post2   = (const float*)d_in[8];
    float* out = (float*)d_out;

    size_t need = (size_t)N_NODES * 64           // u8
                + (size_t)N_NODES * 64 * 2       // v bf16
                + (64 * 320 + 64 * 16 + 64 * 64) * 2;
    if (ws_size < need) return;   // ~12.05 MiB
    unsigned char*  u8p    = (unsigned char*)d_ws;                      // [N][64] u8
    unsigned short* vbf    = (unsigned short*)(u8p + (size_t)N_NODES * 64);  // [N][64] bf16
    unsigned short* wfullT = vbf + (size_t)N_NODES * 64;                // [64][320]
    unsigned short* w3T    = wfullT + 64 * 320;                         // [64][16]
    unsigned short* wp2T   = w3T + 64 * 16;                             // [64][64]

    double ld = log(16.0 + 1.0);                          // log(D+1)
    const double AVG = 2.302585092994046;
    float c1 = (float)(ld / AVG);
    float c2 = (float)(AVG / ld);

    k_prep<<<GRID_PREP, 256, 0, stream>>>(h, W_pre, b_pre, W_post1, W_post2,
                                          u8p, vbf, wfullT, w3T, wp2T, c1, c2);
    k_main<<<GRID_MAIN, 256, 0, stream>>>(h, edge_attr, nbr_idx, b_post1, b_post2,
                                          u8p, vbf, wfullT, w3T, wp2T, out);
}

// Round 17
// 67.015 us; speedup vs baseline: 1.7346x; 1.7346x over previous
//
#include <hip/hip_runtime.h>
#include <hip/hip_bf16.h>
#include <math.h>
#include <stdint.h>

// PNA layer, R17: persistent 4-group pipeline with ZERO-REGISTER staging.
// R16 proved the convoy theory (BW 1.5->2.06 TB/s) but spilled (96B/thread
// scratch). Fix: u8/v prefetch via __builtin_amdgcn_global_load_lds (per-lane
// global src -> wave-uniform LDS dest, 0 VGPR held), NITER loop fully unrolled.
//   u = h@W1 + b_pre -> offset-int8 (scale 16); v = h@W2 (bf16)
//   per group (16 nodes): acc = mfma32x32x16(ea,W3,0); e = relu(acc+u/16-8+v)
//   agg=[mean,max,min,std]; y1 = relu([h,agg]@Wfull + b1); out = y1@Wp2 + b2 + h
// MFMA layouts: 16x16x32 (m89-verified), 32x32x16 C/D (m74/m101-verified).

#define N_NODES 65536
#define NBLK (N_NODES / 16)       // 4096 groups
#define NITER 4
#define GRID_MAIN (NBLK / NITER)  // 1024 persistent blocks
#define GRID_PREP (NBLK + 64)
#define ASTRIDE 348   // A_lds row stride (u16)
#define YSTRIDE 76    // y1_lds row stride (u16)

typedef float f32x4 __attribute__((ext_vector_type(4)));
typedef float f32x16 __attribute__((ext_vector_type(16)));
typedef short s16x8 __attribute__((ext_vector_type(8)));
typedef unsigned short us4 __attribute__((ext_vector_type(4)));

#define GLL16(SRC, DST)                                                        \
    __builtin_amdgcn_global_load_lds(                                          \
        (const __attribute__((address_space(1))) void*)(SRC),                  \
        (__attribute__((address_space(3))) void*)(DST), 16, 0, 0)

__device__ __forceinline__ unsigned short f2bf(float f) {     // manual RNE
    union { float f; unsigned int u; } v; v.f = f;
    unsigned int r = v.u + 0x7fffu + ((v.u >> 16) & 1u);
    return (unsigned short)(r >> 16);
}
__device__ __forceinline__ unsigned short f2bfh(float f) {    // compiler cvt
    __hip_bfloat16 b = __float2bfloat16(f);
    union { __hip_bfloat16 b; unsigned short u; } v; v.b = b; return v.u;
}
__device__ __forceinline__ float bf2f(unsigned short u) {
    union { unsigned int u; float f; } v; v.u = ((unsigned int)u) << 16; return v.f;
}
__device__ __forceinline__ unsigned char enc_u8(float x) {    // offset-int8, scale 16
    int q = __float2int_rn(x * 16.f) + 128;
    q = q < 0 ? 0 : (q > 255 ? 255 : q);
    return (unsigned char)q;
}

// ---------------- prep: u/v via MFMA (blocks < NBLK) + weight transpose ----------------
__global__ __launch_bounds__(256) void k_prep(const float* __restrict__ h,
                                              const float* __restrict__ Wpre,
                                              const float* __restrict__ b_pre,
                                              const float* __restrict__ Wp1,
                                              const float* __restrict__ Wp2,
                                              unsigned char* __restrict__ u8,
                                              unsigned short* __restrict__ vbf,
                                              unsigned short* __restrict__ wfullT,
                                              unsigned short* __restrict__ w3T,
                                              unsigned short* __restrict__ wp2T,
                                              float c1, float c2) {
    int t = threadIdx.x;
    if (blockIdx.x >= NBLK) {
        int c = blockIdx.x - NBLK;     // output col 0..63
        for (int k = t; k < 320; k += 256) {
            float v;
            if (k < 64) v = Wp1[k * 64 + c];
            else {
                int kk = k - 64;
                v = Wp1[(64 + kk) * 64 + c] + c1 * Wp1[(320 + kk) * 64 + c]
                                            + c2 * Wp1[(576 + kk) * 64 + c];
            }
            wfullT[c * 320 + k] = f2bf(v);
        }
        if (t < 16)              w3T[c * 16 + t]         = f2bf(Wpre[(128 + t) * 64 + c]);
        if (t >= 64 && t < 128)  wp2T[c * 64 + (t - 64)] = f2bf(Wp2[(t - 64) * 64 + c]);
        return;
    }

    // ---- uv blocks: [u|v] = h @ [W1|W2], 16 nodes, 4 waves x 32 cols ----
    __shared__ unsigned short hl[16 * 68];
    int lane = t & 63;
    int wv = __builtin_amdgcn_readfirstlane(t) >> 6;   // wave id (uniform)
    int c = lane & 15, g = lane >> 4;
    int node0 = blockIdx.x * 16;
    {
        int r = t >> 4, q = t & 15;
        float4 hv = *((const float4*)(h + (size_t)node0 * 64) + t);
        us4 o;
        o.x = f2bfh(hv.x); o.y = f2bfh(hv.y); o.z = f2bfh(hv.z); o.w = f2bfh(hv.w);
        *(us4*)&hl[r * 68 + q * 4] = o;
    }
    s16x8 bf[2][2];
    int woff = (wv < 2) ? 0 : 64;
    #pragma unroll
    for (int i2 = 0; i2 < 2; ++i2) {
        int wcol = ((wv & 1) * 32) + i2 * 16 + c;
        #pragma unroll
        for (int ks = 0; ks < 2; ++ks) {
            #pragma unroll
            for (int j = 0; j < 8; ++j)
                bf[i2][ks][j] = (short)f2bfh(Wpre[(woff + ks * 32 + g * 8 + j) * 64 + wcol]);
        }
    }
    __syncthreads();
    f32x4 acc0 = {0.f, 0.f, 0.f, 0.f}, acc1 = {0.f, 0.f, 0.f, 0.f};
    #pragma unroll
    for (int ks = 0; ks < 2; ++ks) {
        s16x8 a = *(const s16x8*)&hl[c * 68 + ks * 32 + g * 8];
        acc0 = __builtin_amdgcn_mfma_f32_16x16x32_bf16(a, bf[0][ks], acc0, 0, 0, 0);
        acc1 = __builtin_amdgcn_mfma_f32_16x16x32_bf16(a, bf[1][ks], acc1, 0, 0, 0);
    }
    #pragma unroll
    for (int i2 = 0; i2 < 2; ++i2) {
        int dcol = ((wv & 1) * 32) + i2 * 16 + c;
        const f32x4& av = i2 ? acc1 : acc0;
        if (wv < 2) {
            float bp = b_pre[dcol];
            #pragma unroll
            for (int i = 0; i < 4; ++i) {
                int row = g * 4 + i;
                u8[(size_t)(node0 + row) * 64 + dcol] = enc_u8(av[i] + bp);
            }
        } else {
            #pragma unroll
            for (int i = 0; i < 4; ++i) {
                int row = g * 4 + i;
                vbf[(size_t)(node0 + row) * 64 + dcol] = f2bfh(av[i]);
            }
        }
    }
}

// ---------------- fused main: persistent, NITER pipelined groups per block ----------------
__global__ __launch_bounds__(256, 3) void k_main(
    const float* __restrict__ h,
    const float* __restrict__ edge_attr,
    const int* __restrict__ nbr_idx,
    const float* __restrict__ b_post1,
    const float* __restrict__ b_post2,
    const unsigned char* __restrict__ u8,       // [N][64] offset-int8 (4 MB, L2-fit)
    const unsigned short* __restrict__ vbf,     // [N][64] bf16
    const unsigned short* __restrict__ wfullT,  // [64][320] bf16 (L2-resident)
    const unsigned short* __restrict__ w3T,     // [64][16]
    const unsigned short* __restrict__ wp2T,    // [64][64]
    float* __restrict__ out) {
    __shared__ unsigned char  u_lds[2][16384];       // 32768 B  [256 rows][64 B]
    __shared__ unsigned short v_lds[2][1024];        // 4096 B   [16][64]
    __shared__ unsigned short A_lds[16 * ASTRIDE];   // 11136 B
    __shared__ unsigned short y1_lds[16 * YSTRIDE];  // 2432 B   -> 50432 B total

    int t = threadIdx.x;
    int lane = t & 63;
    int wv = __builtin_amdgcn_readfirstlane(t) >> 6;    // wave id (uniform)
    int c = lane & 15;          // 16x16 frag col / A-row
    int g = lane >> 4;          // 16x16 k-group
    int l32 = lane & 31;        // 32x32 frag row/col
    int h2 = lane >> 5;         // 32x32 k-half
    int ct = wv & 1;            // 32-col tile (uniform)
    int wr = wv >> 1;           // row-tile base (uniform)
    int colb = ct * 32 + l32;   // pretrans output col
    int col16 = wv * 16 + c;    // post1/post2 output col
    int ch = t & 3;             // staging 16B chunk
    int srow = t >> 2;          // staging row base (+64*i)

    s16x8 w3b = *(const s16x8*)&w3T[colb * 16 + h2 * 8];
    float b1c = b_post1[col16];
    float b2c = b_post2[col16];

    int grp0 = blockIdx.x * NITER;
    float4 xaC[4], xbC[4];
    float4 hC;
    int jc[4];

    // ---------- prologue: GLL-stage group grp0 into buf0; regs for grp0 ----------
    {
        int j0[4];
        #pragma unroll
        for (int i = 0; i < 4; ++i)
            j0[i] = nbr_idx[(size_t)grp0 * 256 + srow + 64 * i];
        #pragma unroll
        for (int i = 0; i < 4; ++i)
            GLL16(u8 + ((size_t)j0[i] << 6) + ch * 16,
                  &u_lds[0][i * 4096 + wv * 1024]);
        if (wv < 2)
            GLL16((const char*)vbf + ((size_t)grp0 << 11) + (size_t)t * 16,
                  &v_lds[0][wv * 512]);   // u16 index: 512 u16 = 1024 B per wave
        const char* eb = (const char*)edge_attr
                       + ((size_t)grp0 * 256 + wr * 32 + l32) * 64 + h2 * 32;
        #pragma unroll
        for (int k = 0; k < 4; ++k) {
            xaC[k] = *(const float4*)(eb + k * 4096);
            xbC[k] = *(const float4*)(eb + k * 4096 + 16);
        }
        hC = *((const float4*)(h + (size_t)grp0 * 1024) + t);
        #pragma unroll
        for (int i = 0; i < 4; ++i)
            jc[i] = nbr_idx[(size_t)(grp0 + 1) * 256 + srow + 64 * i];
        {   // h(grp0) -> A_lds
            int r = t >> 4, q = t & 15;
            us4 o;
            o.x = f2bfh(hC.x); o.y = f2bfh(hC.y); o.z = f2bfh(hC.z); o.w = f2bfh(hC.w);
            *(us4*)&A_lds[r * ASTRIDE + q * 4] = o;
        }
    }
    __syncthreads();   // drains GLL buf0 + edge/h loads

    #pragma unroll
    for (int it = 0; it < NITER; ++it) {
        const int b = it & 1;
        int grp = grp0 + it;
        size_t node0 = (size_t)grp * 16;
        const bool pf = (it + 1 < NITER);
        int grpn = grp + 1;

        // ---- prefetch group it+1: GLL u8/v (0 regs) + edges/h to regs ----
        float4 xaN[4], xbN[4];
        float4 hN = {0.f, 0.f, 0.f, 0.f};
        int jn[4] = {0, 0, 0, 0};
        if (pf) {
            #pragma unroll
            for (int i = 0; i < 4; ++i)
                GLL16(u8 + ((size_t)jc[i] << 6) + ch * 16,
                      &u_lds[b ^ 1][i * 4096 + wv * 1024]);
            if (wv < 2)
                GLL16((const char*)vbf + ((size_t)grpn << 11) + (size_t)t * 16,
                      &v_lds[b ^ 1][wv * 512]);
            const char* ebn = (const char*)edge_attr
                            + ((size_t)grpn * 256 + wr * 32 + l32) * 64 + h2 * 32;
            #pragma unroll
            for (int k = 0; k < 4; ++k) {
                xaN[k] = *(const float4*)(ebn + k * 4096);
                xbN[k] = *(const float4*)(ebn + k * 4096 + 16);
            }
            hN = *((const float4*)(h + (size_t)grpn * 1024) + t);
            if (it + 2 < NITER) {
                #pragma unroll
                for (int i = 0; i < 4; ++i)
                    jn[i] = nbr_idx[(size_t)(grp + 2) * 256 + srow + 64 * i];
            }
        }

        // ---- tiles: 4x 32x32x16 MFMA + stats on buf b ----
#define TILEC(IT) {                                                            \
    int rt = wr + 2 * (IT);                                                    \
    s16x8 a;                                                                   \
    a[0] = (short)f2bfh(xaC[IT].x); a[1] = (short)f2bfh(xaC[IT].y);            \
    a[2] = (short)f2bfh(xaC[IT].z); a[3] = (short)f2bfh(xaC[IT].w);            \
    a[4] = (short)f2bfh(xbC[IT].x); a[5] = (short)f2bfh(xbC[IT].y);            \
    a[6] = (short)f2bfh(xbC[IT].z); a[7] = (short)f2bfh(xbC[IT].w);            \
    f32x16 acc = {};                                                           \
    acc = __builtin_amdgcn_mfma_f32_32x32x16_bf16(a, w3b, acc, 0, 0, 0);       \
    const unsigned char* ur = &u_lds[b][(rt * 32 + 4 * h2) * 64 + colb];       \
    float uf[16];                                                              \
    _Pragma("unroll")                                                          \
    for (int q = 0; q < 4; ++q) {                                              \
        uf[4 * q + 0] = (float)ur[(8 * q + 0) * 64];                           \
        uf[4 * q + 1] = (float)ur[(8 * q + 1) * 64];                           \
        uf[4 * q + 2] = (float)ur[(8 * q + 2) * 64];                           \
        uf[4 * q + 3] = (float)ur[(8 * q + 3) * 64];                           \
    }                                                                          \
    float vv0 = bf2f(v_lds[b][(2 * rt + 0) * 64 + colb]) - 8.f;                \
    float vv1 = bf2f(v_lds[b][(2 * rt + 1) * 64 + colb]) - 8.f;                \
    float e0  = fmaxf(fmaf(uf[0],  0.0625f, acc[0]  + vv0), 0.f);              \
    float e1  = fmaxf(fmaf(uf[1],  0.0625f, acc[1]  + vv0), 0.f);              \
    float e2  = fmaxf(fmaf(uf[2],  0.0625f, acc[2]  + vv0), 0.f);              \
    float e3  = fmaxf(fmaf(uf[3],  0.0625f, acc[3]  + vv0), 0.f);              \
    float e4  = fmaxf(fmaf(uf[4],  0.0625f, acc[4]  + vv0), 0.f);              \
    float e5  = fmaxf(fmaf(uf[5],  0.0625f, acc[5]  + vv0), 0.f);              \
    float e6  = fmaxf(fmaf(uf[6],  0.0625f, acc[6]  + vv0), 0.f);              \
    float e7  = fmaxf(fmaf(uf[7],  0.0625f, acc[7]  + vv0), 0.f);              \
    float e8  = fmaxf(fmaf(uf[8],  0.0625f, acc[8]  + vv1), 0.f);              \
    float e9  = fmaxf(fmaf(uf[9],  0.0625f, acc[9]  + vv1), 0.f);              \
    float e10 = fmaxf(fmaf(uf[10], 0.0625f, acc[10] + vv1), 0.f);              \
    float e11 = fmaxf(fmaf(uf[11], 0.0625f, acc[11] + vv1), 0.f);              \
    float e12 = fmaxf(fmaf(uf[12], 0.0625f, acc[12] + vv1), 0.f);              \
    float e13 = fmaxf(fmaf(uf[13], 0.0625f, acc[13] + vv1), 0.f);              \
    float e14 = fmaxf(fmaf(uf[14], 0.0625f, acc[14] + vv1), 0.f);              \
    float e15 = fmaxf(fmaf(uf[15], 0.0625f, acc[15] + vv1), 0.f);              \
    float s1a = ((e0 + e1) + (e2 + e3)) + ((e4 + e5) + (e6 + e7));             \
    float s2a = fmaf(e0, e0, fmaf(e1, e1, fmaf(e2, e2, e3 * e3)))              \
              + fmaf(e4, e4, fmaf(e5, e5, fmaf(e6, e6, e7 * e7)));             \
    float mxa = fmaxf(fmaxf(fmaxf(e0, e1), fmaxf(e2, e3)),                     \
                      fmaxf(fmaxf(e4, e5), fmaxf(e6, e7)));                    \
    float mna = fminf(fminf(fminf(e0, e1), fminf(e2, e3)),                     \
                      fminf(fminf(e4, e5), fminf(e6, e7)));                    \
    float s1b = ((e8 + e9) + (e10 + e11)) + ((e12 + e13) + (e14 + e15));       \
    float s2b = fmaf(e8, e8, fmaf(e9, e9, fmaf(e10, e10, e11 * e11)))          \
              + fmaf(e12, e12, fmaf(e13, e13, fmaf(e14, e14, e15 * e15)));     \
    float mxb = fmaxf(fmaxf(fmaxf(e8, e9), fmaxf(e10, e11)),                   \
                      fmaxf(fmaxf(e12, e13), fmaxf(e14, e15)));                \
    float mnb = fminf(fminf(fminf(e8, e9), fminf(e10, e11)),                   \
                      fminf(fminf(e12, e13), fminf(e14, e15)));                \
    s1a += __shfl_xor(s1a, 32); s2a += __shfl_xor(s2a, 32);                    \
    mxa = fmaxf(mxa, __shfl_xor(mxa, 32)); mna = fminf(mna, __shfl_xor(mna, 32)); \
    s1b += __shfl_xor(s1b, 32); s2b += __shfl_xor(s2b, 32);                    \
    mxb = fmaxf(mxb, __shfl_xor(mxb, 32)); mnb = fminf(mnb, __shfl_xor(mnb, 32)); \
    float S1 = h2 ? s1b : s1a;                                                 \
    float S2 = h2 ? s2b : s2a;                                                 \
    float MX = h2 ? mxb : mxa;                                                 \
    float MN = h2 ? mnb : mna;                                                 \
    float M  = S1 * 0.0625f;                                                   \
    float SD = sqrtf(fmaxf(fmaf(-M, M, S2 * 0.0625f), 0.f) + 1e-5f);           \
    unsigned short* pd = &A_lds[(2 * rt + h2) * ASTRIDE + 64 + colb];          \
    pd[0]   = f2bfh(M);                                                        \
    pd[64]  = f2bfh(MX);                                                       \
    pd[128] = f2bfh(MN);                                                       \
    pd[192] = f2bfh(SD);                                                       \
}
        TILEC(0)
        TILEC(1)
        TILEC(2)
        TILEC(3)
#undef TILEC

        // ---- hoist post1 weight loads (drain with barrier) ----
        s16x8 wf[10];
        #pragma unroll
        for (int ks = 0; ks < 10; ++ks)
            wf[ks] = *(const s16x8*)&wfullT[col16 * 320 + ks * 32 + g * 8];
        __syncthreads();   // barrier(1): agg visible; GLL buf b^1 + xaN drained

        // ---- post1: y1 = relu([h,agg]@Wfull + b1), K=320 ----
        {
            f32x4 y1 = {0.f, 0.f, 0.f, 0.f};
            #pragma unroll
            for (int ks = 0; ks < 10; ++ks) {
                s16x8 a = *(const s16x8*)&A_lds[c * ASTRIDE + ks * 32 + g * 8];
                y1 = __builtin_amdgcn_mfma_f32_16x16x32_bf16(a, wf[ks], y1, 0, 0, 0);
            }
            #pragma unroll
            for (int i = 0; i < 4; ++i)
                y1_lds[(g * 4 + i) * YSTRIDE + col16] = f2bfh(fmaxf(y1[i] + b1c, 0.f));
        }
        s16x8 wp0 = *(const s16x8*)&wp2T[col16 * 64 + 0 * 32 + g * 8];
        s16x8 wp1 = *(const s16x8*)&wp2T[col16 * 64 + 1 * 32 + g * 8];
        __syncthreads();   // barrier(2): y1 visible; A_lds reads done

        // ---- h(it+1) -> A_lds h region (A free until next post1) ----
        if (pf) {
            int r = t >> 4, q = t & 15;
            us4 o;
            o.x = f2bfh(hN.x); o.y = f2bfh(hN.y); o.z = f2bfh(hN.z); o.w = f2bfh(hN.w);
            *(us4*)&A_lds[r * ASTRIDE + q * 4] = o;
        }

        // ---- post2 + residual ----
        {
            f32x4 o = {0.f, 0.f, 0.f, 0.f};
            s16x8 a0 = *(const s16x8*)&y1_lds[c * YSTRIDE + 0 * 32 + g * 8];
            s16x8 a1 = *(const s16x8*)&y1_lds[c * YSTRIDE + 1 * 32 + g * 8];
            o = __builtin_amdgcn_mfma_f32_16x16x32_bf16(a0, wp0, o, 0, 0, 0);
            o = __builtin_amdgcn_mfma_f32_16x16x32_bf16(a1, wp1, o, 0, 0, 0);
            #pragma unroll
            for (int i = 0; i < 4; ++i) {
                int r = g * 4 + i;
                out[(node0 + r) * 64 + col16] =
                    o[i] + b2c + h[(node0 + r) * 64 + col16];
            }
        }

        // ---- rotate register state (SSA under full unroll) ----
        if (pf) {
            #pragma unroll
            for (int k = 0; k < 4; ++k) { xaC[k] = xaN[k]; xbC[k] = xbN[k]; }
            hC = hN;
            #pragma unroll
            for (int i = 0; i < 4; ++i) jc[i] = jn[i];
        }
    }
}

extern "C" void kernel_launch(void* const* d_in, const int* in_sizes, int n_in,
                              void* d_out, int out_size, void* d_ws, size_t ws_size,
                              hipStream_t stream) {
    const float* h         = (const float*)d_in[0];
    const float* edge_attr = (const float*)d_in[1];
    const int*   nbr_idx   = (const int*)d_in[2];
    const float* W_pre     = (const float*)d_in[3];
    const float* b_pre     = (const float*)d_in[4];
    const float* W_post1   = (const float*)d_in[5];
    const float* b_post1   = (const float*)d_in[6];
    const float* W_post2   = (const float*)d_in[7];
    const float* b_post2   = (const float*)d_in[8];
    float* out = (float*)d_out;

    size_t need = (size_t)N_NODES * 64           // u8
                + (size_t)N_NODES * 64 * 2       // v bf16
                + (64 * 320 + 64 * 16 + 64 * 64) * 2;
    if (ws_size < need) return;   // ~12.05 MiB
    unsigned char*  u8p    = (unsigned char*)d_ws;                      // [N][64] u8
    unsigned short* vbf    = (unsigned short*)(u8p + (size_t)N_NODES * 64);  // [N][64] bf16
    unsigned short* wfullT = vbf + (size_t)N_NODES * 64;                // [64][320]
    unsigned short* w3T    = wfullT + 64 * 320;                         // [64][16]
    unsigned short* wp2T   = w3T + 64 * 16;                             // [64][64]

    double ld = log(16.0 + 1.0);                          // log(D+1)
    const double AVG = 2.302585092994046;
    float c1 = (float)(ld / AVG);
    float c2 = (float)(AVG / ld);

    k_prep<<<GRID_PREP, 256, 0, stream>>>(h, W_pre, b_pre, W_post1, W_post2,
                                          u8p, vbf, wfullT, w3T, wp2T, c1, c2);
    k_main<<<GRID_MAIN, 256, 0, stream>>>(h, edge_attr, nbr_idx, b_post1, b_post2,
                                          u8p, vbf, wfullT, w3T, wp2T, out);
}